// Round 4
// baseline (344.085 us; speedup 1.0000x reference)
//
#include <hip/hip_runtime.h>

// SQDDPG mixer, MI355X. Round 4: occupancy push + prep/pack fusion.
//
// Frozen validated facts (R2/R3 passes): threefry partitionable, bits=o0^o1,
// counter (0, b*128+n); stable ranks; coalition slot j <- qs[inv_l[j]];
// output agent n reads prefix-row pos_l[n]; h1 scatter formula; B-frag pack
// order: slot (t,u,L) elem j -> B[k=t*32+(L>>4)*8+j][n=u*16+(L&15)].
//
// R4 changes:
//  - main: layer-1 A-frags built in registers (X_l LDS buffer deleted),
//    LDS 55.8->36 KB, __launch_bounds__(256,4) -> target 4 blocks/CU.
//  - prep: 256 blocks x 4 b, K-loop unroll 16 (ILP), pack kernel fused in
//    as blocks 256..303. One launch fewer.

#define A_N   8
#define NA_N  16
#define S_N   16
#define SD    256
#define EMB   256
#define B_TOT 1024

typedef __bf16 bf16x8 __attribute__((ext_vector_type(8)));
typedef float  f32x4  __attribute__((ext_vector_type(4)));

__device__ __forceinline__ f32x4 splat4(float v) {
  f32x4 x; x[0] = v; x[1] = v; x[2] = v; x[3] = v; return x;
}
__device__ __forceinline__ bf16x8 zero8() {
  bf16x8 z;
#pragma unroll
  for (int j = 0; j < 8; ++j) z[j] = (__bf16)0.0f;
  return z;
}

// ---------------------------------------------------------------------------
// JAX threefry2x32, key = (0, 42); partitionable draw: bits = o0 ^ o1.
// ---------------------------------------------------------------------------
__device__ __forceinline__ float jax_uniform(unsigned idx) {
  const unsigned ks0 = 0u, ks1 = 42u, ks2 = 0x1BD11BDAu ^ 42u;
  unsigned x0 = 0u + ks0;
  unsigned x1 = idx + ks1;
#define TF_RND(r) { x0 += x1; x1 = (x1 << (r)) | (x1 >> (32 - (r))); x1 ^= x0; }
  TF_RND(13) TF_RND(15) TF_RND(26) TF_RND(6)  x0 += ks1; x1 += ks2 + 1u;
  TF_RND(17) TF_RND(29) TF_RND(16) TF_RND(24) x0 += ks2; x1 += ks0 + 2u;
  TF_RND(13) TF_RND(15) TF_RND(26) TF_RND(6)  x0 += ks0; x1 += ks1 + 3u;
  TF_RND(17) TF_RND(29) TF_RND(16) TF_RND(24) x0 += ks1; x1 += ks2 + 4u;
  TF_RND(13) TF_RND(15) TF_RND(26) TF_RND(6)  x0 += ks2; x1 += ks0 + 5u;
#undef TF_RND
  const unsigned bits = x0 ^ x1;
  return __uint_as_float((bits >> 9) | 0x3F800000u) - 1.0f;
}

// ---------------------------------------------------------------------------
// Fused prep (blocks 0..255: 4 b's each) + weight pack (blocks 256..303).
// ---------------------------------------------------------------------------
__global__ __launch_bounds__(256) void prep_pack_kernel(
    const float* __restrict__ states, const float* __restrict__ W1,
    const float* __restrict__ b1, const float* __restrict__ W2,
    const float* __restrict__ Vw1, const float* __restrict__ Vb1,
    const float* __restrict__ Vw2, const float* __restrict__ Vb2,
    float* __restrict__ sW, float* __restrict__ vout,
    __bf16* __restrict__ W1b_bf, __bf16* __restrict__ W2_bf) {
  const int n = threadIdx.x;

  if (blockIdx.x >= 256) {
    // ---- pack path: bf16 B-fragment order ----
    const int ts = (blockIdx.x - 256) * 256 + n;    // 0..12287
    if (ts < 4096) {                                // W1 bottom: t=0..3
      const int t = ts >> 10, rem = ts & 1023, u = rem >> 6, L = rem & 63;
      const int q = L >> 4, l15 = L & 15;
#pragma unroll
      for (int j = 0; j < 8; ++j) {
        const int k = t * 32 + q * 8 + j, nn = u * 16 + l15;
        W1b_bf[ts * 8 + j] = (__bf16)W1[(SD + k) * EMB + nn];
      }
    } else {                                        // W2: t=0..7
      const int ts2 = ts - 4096;
      const int t = ts2 >> 10, rem = ts2 & 1023, u = rem >> 6, L = rem & 63;
      const int q = L >> 4, l15 = L & 15;
#pragma unroll
      for (int j = 0; j < 8; ++j) {
        const int k = t * 32 + q * 8 + j, nn = u * 16 + l15;
        W2_bf[ts2 * 8 + j] = (__bf16)W2[k * EMB + nn];
      }
    }
    return;
  }

  // ---- prep path ----
  __shared__ float st_l[4][SD];
  __shared__ float red_l[4][4];
  const int b0 = blockIdx.x * 4;

#pragma unroll
  for (int i = 0; i < 4; ++i) st_l[i][n] = states[(b0 + i) * SD + n];
  __syncthreads();

  float aS[4], aV[4];
  const float b1n = b1[n], vb1n = Vb1[n];
#pragma unroll
  for (int i = 0; i < 4; ++i) { aS[i] = b1n; aV[i] = vb1n; }

#pragma unroll 16
  for (int k = 0; k < SD; ++k) {
    const float wv = W1[k * EMB + n];
    const float vw = Vw1[k * EMB + n];
#pragma unroll
    for (int i = 0; i < 4; ++i) {
      const float s = st_l[i][k];
      aS[i] = fmaf(s, wv, aS[i]);
      aV[i] = fmaf(s, vw, aV[i]);
    }
  }
#pragma unroll
  for (int i = 0; i < 4; ++i) sW[(b0 + i) * EMB + n] = aS[i];

  const float vw2 = Vw2[n];
#pragma unroll
  for (int i = 0; i < 4; ++i) {
    float c = fmaxf(aV[i], 0.f) * vw2;
#pragma unroll
    for (int off = 32; off; off >>= 1) c += __shfl_down(c, off);
    if ((n & 63) == 0) red_l[i][n >> 6] = c;
  }
  __syncthreads();
  if (n < 4)
    vout[b0 + n] = red_l[n][0] + red_l[n][1] + red_l[n][2] + red_l[n][3] + Vb2[0];
}

// ---------------------------------------------------------------------------
// Main: 1024 blocks (one per b), 256 threads = 4 waves. Two passes of M=64.
// Layer-1 A-frags built in registers from qs_bf + inv_l (no X_l buffer).
// ---------------------------------------------------------------------------
__global__ __launch_bounds__(256, 4) void main_kernel(
    const float* __restrict__ agent_qs, const float* __restrict__ b2g,
    const float* __restrict__ W3, const float* __restrict__ b3,
    const float* __restrict__ sW, const float* __restrict__ vv,
    const __bf16* __restrict__ W1b_bf, const __bf16* __restrict__ W2_bf,
    float* __restrict__ out) {
  __shared__ bf16x8 h1_l[32 * 64];      // 32 KB: layer2 A-frags (M=64,K=256)
  __shared__ __attribute__((aligned(16))) __bf16 qs_bf[A_N * NA_N];
  __shared__ float u_l[128];
  __shared__ int   inv_l[128];          // inv_l[s*8+a] = rank of agent a
  __shared__ int   pos_l[128];          // pos_l[s*8+r] = agent with rank r
  __shared__ float adv_part[4][64];
  __shared__ float marg_l[128];         // marginal[s][prefix-row]

  const int b = blockIdx.x;
  const int n = threadIdx.x;
  const int w = n >> 6, L = n & 63, q = L >> 4, l15 = L & 15;

  if (n < 128) {
    qs_bf[n] = (__bf16)agent_qs[b * 128 + n];
    u_l[n] = jax_uniform((unsigned)(b * 128 + n));
  }
  // per-wave column constants (cols c = (w*4+un)*16 + l15)
  float sWv[4];
#pragma unroll
  for (int un = 0; un < 4; ++un) sWv[un] = sW[b * EMB + (w * 4 + un) * 16 + l15];
  __syncthreads();

  if (n < 128) {
    const int s = n >> 3, a = n & 7;
    const float u = u_l[n];
    int r = 0;
#pragma unroll
    for (int a2 = 0; a2 < A_N; ++a2) {
      const float u2 = u_l[s * 8 + a2];
      r += (u2 < u || (u2 == u && a2 < a)) ? 1 : 0;
    }
    inv_l[n] = r;
    pos_l[s * 8 + r] = a;
  }
  __syncthreads();

  const int i_pref  = l15 & 7;     // prefix length of this lane's row
  const int sl_half = l15 >> 3;    // which s within the mt pair
  const int jq      = q >> 1;      // jcoal low bit
  const int na0     = (q & 1) * 8; // action sub-block

  for (int p = 0; p < 2; ++p) {
    // ---- layer 1: (64x128) @ W1b (128x256), C init sW[col] ----
    f32x4 acc[4][4];
#pragma unroll
    for (int un = 0; un < 4; ++un) {
#pragma unroll
      for (int mt = 0; mt < 4; ++mt) acc[mt][un] = splat4(sWv[un]);
    }
#pragma unroll
    for (int t = 0; t < 4; ++t) {
      const int jcoal = t * 2 + jq;
      const bool on = (jcoal <= i_pref);
      bf16x8 bfr[4];
#pragma unroll
      for (int un = 0; un < 4; ++un)
        bfr[un] = *(const bf16x8*)&W1b_bf[((t * 16 + w * 4 + un) * 64 + L) * 8];
#pragma unroll
      for (int mt = 0; mt < 4; ++mt) {
        const int s_loc = mt * 2 + sl_half;
        const int ag = inv_l[(p * 8 + s_loc) * 8 + jcoal];
        const bf16x8 qv = *(const bf16x8*)&qs_bf[ag * NA_N + na0];
        const bf16x8 af = on ? qv : zero8();
#pragma unroll
        for (int un = 0; un < 4; ++un)
          acc[mt][un] = __builtin_amdgcn_mfma_f32_16x16x32_bf16(
              af, bfr[un], acc[mt][un], 0, 0, 0);
      }
    }

    // ---- epilogue: relu -> bf16 scatter into layer2 A-frag layout ----
    {
      __bf16* h1e = (__bf16*)h1_l;
#pragma unroll
      for (int un = 0; un < 4; ++un) {
        const int c = (w * 4 + un) * 16 + l15;
        const int t2 = c >> 5, q2 = (c >> 3) & 3, j2 = l15 & 7;
#pragma unroll
        for (int mt = 0; mt < 4; ++mt) {
#pragma unroll
          for (int r = 0; r < 4; ++r) {
            const float v = fmaxf(acc[mt][un][r], 0.f);
            h1e[(((t2 * 4 + mt) * 64) + q2 * 16 + q * 4 + r) * 8 + j2] =
                (__bf16)v;
          }
        }
      }
    }
    __syncthreads();

    // ---- layer 2: (64x256) @ W2 (256x256), C init b2[col] ----
#pragma unroll
    for (int un = 0; un < 4; ++un) {
      const float bv = b2g[(w * 4 + un) * 16 + l15];
#pragma unroll
      for (int mt = 0; mt < 4; ++mt) acc[mt][un] = splat4(bv);
    }
#pragma unroll
    for (int t = 0; t < 8; ++t) {
      bf16x8 bfr[4];
#pragma unroll
      for (int un = 0; un < 4; ++un)
        bfr[un] = *(const bf16x8*)&W2_bf[((t * 16 + w * 4 + un) * 64 + L) * 8];
#pragma unroll
      for (int mt = 0; mt < 4; ++mt) {
        const bf16x8 af = h1_l[(t * 4 + mt) * 64 + L];
#pragma unroll
        for (int un = 0; un < 4; ++un)
          acc[mt][un] = __builtin_amdgcn_mfma_f32_16x16x32_bf16(
              af, bfr[un], acc[mt][un], 0, 0, 0);
      }
    }

    // ---- layer 3: relu * W3, reduce 16 cols per quad ----
    float w3v[4];
#pragma unroll
    for (int un = 0; un < 4; ++un) w3v[un] = W3[(w * 4 + un) * 16 + l15];
#pragma unroll
    for (int mt = 0; mt < 4; ++mt) {
#pragma unroll
      for (int r = 0; r < 4; ++r) {
        float sum = 0.f;
#pragma unroll
        for (int un = 0; un < 4; ++un)
          sum = fmaf(fmaxf(acc[mt][un][r], 0.f), w3v[un], sum);
#pragma unroll
        for (int off = 1; off < 16; off <<= 1) sum += __shfl_xor(sum, off);
        if (l15 == 0) adv_part[w][mt * 16 + q * 4 + r] = sum;
      }
    }
    __syncthreads();
    if (n < 64)
      marg_l[p * 64 + n] = adv_part[0][n] + adv_part[1][n] +
                           adv_part[2][n] + adv_part[3][n];
    __syncthreads();
  }

  // ---- gather: agent a reads prefix-row pos_l[s*8+a] (validated) ----
  if (n < A_N) {
    float sh = 0.f;
#pragma unroll
    for (int s = 0; s < S_N; ++s) sh += marg_l[s * 8 + pos_l[s * 8 + n]];
    out[b * A_N + n] = sh * (1.f / 16.f) + b3[0] + vv[b];
  }
}

// ---------------------------------------------------------------------------
extern "C" void kernel_launch(void* const* d_in, const int* in_sizes, int n_in,
                              void* d_out, int out_size, void* d_ws,
                              size_t ws_size, hipStream_t stream) {
  const float* states   = (const float*)d_in[0];
  const float* agent_qs = (const float*)d_in[1];
  const float* W1       = (const float*)d_in[2];
  const float* b1       = (const float*)d_in[3];
  const float* W2       = (const float*)d_in[4];
  const float* b2       = (const float*)d_in[5];
  const float* W3       = (const float*)d_in[6];
  const float* b3       = (const float*)d_in[7];
  const float* Vw1      = (const float*)d_in[8];
  const float* Vb1      = (const float*)d_in[9];
  const float* Vw2      = (const float*)d_in[10];
  const float* Vb2      = (const float*)d_in[11];
  float* out = (float*)d_out;

  char* ws = (char*)d_ws;
  float*  sW     = (float*)(ws);                     // 1 MB
  float*  vv     = (float*)(ws + 1048576);           // 4 KB
  __bf16* W1b_bf = (__bf16*)(ws + 1052672);          // 64 KB
  __bf16* W2_bf  = (__bf16*)(ws + 1118208);          // 128 KB

  prep_pack_kernel<<<304, 256, 0, stream>>>(states, W1, b1, W2, Vw1, Vb1,
                                            Vw2, Vb2, sW, vv, W1b_bf, W2_bf);
  main_kernel<<<B_TOT, 256, 0, stream>>>(agent_qs, b2, W3, b3, sW, vv,
                                         W1b_bf, W2_bf, out);
}

// Round 5
// 122.644 us; speedup vs baseline: 2.8056x; 2.8056x over previous
//
#include <hip/hip_runtime.h>

// SQDDPG mixer, MI355X. Round 5: kill the spill (R4 post-mortem: (256,4)
// forced 128-reg budget, acc[4][4]=64 AGPRs left 64 VGPRs -> 560 MB scratch
// traffic). Fix: sequential un-halves so only acc[4][2] is live.
//
// Frozen validated facts (R2/R3 passes): threefry partitionable, bits=o0^o1,
// counter (0, b*128+n); stable ranks; coalition slot j <- qs[inv_l[j]];
// output agent n reads prefix-row pos_l[n]; h1 scatter formula; B-frag pack
// order: slot (t,u,L) elem j -> B[k=t*32+(L>>4)*8+j][n=u*16+(L&15)].

#define A_N   8
#define NA_N  16
#define S_N   16
#define SD    256
#define EMB   256
#define B_TOT 1024

typedef __bf16 bf16x8 __attribute__((ext_vector_type(8)));
typedef float  f32x4  __attribute__((ext_vector_type(4)));

__device__ __forceinline__ f32x4 splat4(float v) {
  f32x4 x; x[0] = v; x[1] = v; x[2] = v; x[3] = v; return x;
}
__device__ __forceinline__ bf16x8 zero8() {
  bf16x8 z;
#pragma unroll
  for (int j = 0; j < 8; ++j) z[j] = (__bf16)0.0f;
  return z;
}

// ---------------------------------------------------------------------------
// JAX threefry2x32, key = (0, 42); partitionable draw: bits = o0 ^ o1.
// ---------------------------------------------------------------------------
__device__ __forceinline__ float jax_uniform(unsigned idx) {
  const unsigned ks0 = 0u, ks1 = 42u, ks2 = 0x1BD11BDAu ^ 42u;
  unsigned x0 = 0u + ks0;
  unsigned x1 = idx + ks1;
#define TF_RND(r) { x0 += x1; x1 = (x1 << (r)) | (x1 >> (32 - (r))); x1 ^= x0; }
  TF_RND(13) TF_RND(15) TF_RND(26) TF_RND(6)  x0 += ks1; x1 += ks2 + 1u;
  TF_RND(17) TF_RND(29) TF_RND(16) TF_RND(24) x0 += ks2; x1 += ks0 + 2u;
  TF_RND(13) TF_RND(15) TF_RND(26) TF_RND(6)  x0 += ks0; x1 += ks1 + 3u;
  TF_RND(17) TF_RND(29) TF_RND(16) TF_RND(24) x0 += ks1; x1 += ks2 + 4u;
  TF_RND(13) TF_RND(15) TF_RND(26) TF_RND(6)  x0 += ks2; x1 += ks0 + 5u;
#undef TF_RND
  const unsigned bits = x0 ^ x1;
  return __uint_as_float((bits >> 9) | 0x3F800000u) - 1.0f;
}

// ---------------------------------------------------------------------------
// Prep: 512 blocks x 2 b each (2 blocks/CU, 8 waves/CU; half of R2's L2
// traffic, 4x the latency hiding of the R3/R4 256-block variant).
// ---------------------------------------------------------------------------
__global__ __launch_bounds__(256) void prep_kernel(
    const float* __restrict__ states, const float* __restrict__ W1,
    const float* __restrict__ b1, const float* __restrict__ Vw1,
    const float* __restrict__ Vb1, const float* __restrict__ Vw2,
    const float* __restrict__ Vb2, float* __restrict__ sW,
    float* __restrict__ vout) {
  __shared__ float st_l[2][SD];
  __shared__ float red_l[2][4];
  const int b0 = blockIdx.x * 2;
  const int n = threadIdx.x;

#pragma unroll
  for (int i = 0; i < 2; ++i) st_l[i][n] = states[(b0 + i) * SD + n];
  __syncthreads();

  float aS[2], aV[2];
  const float b1n = b1[n], vb1n = Vb1[n];
#pragma unroll
  for (int i = 0; i < 2; ++i) { aS[i] = b1n; aV[i] = vb1n; }

#pragma unroll 8
  for (int k = 0; k < SD; ++k) {
    const float wv = W1[k * EMB + n];
    const float vw = Vw1[k * EMB + n];
#pragma unroll
    for (int i = 0; i < 2; ++i) {
      const float s = st_l[i][k];
      aS[i] = fmaf(s, wv, aS[i]);
      aV[i] = fmaf(s, vw, aV[i]);
    }
  }
#pragma unroll
  for (int i = 0; i < 2; ++i) sW[(b0 + i) * EMB + n] = aS[i];

  const float vw2 = Vw2[n];
#pragma unroll
  for (int i = 0; i < 2; ++i) {
    float c = fmaxf(aV[i], 0.f) * vw2;
#pragma unroll
    for (int off = 32; off; off >>= 1) c += __shfl_down(c, off);
    if ((n & 63) == 0) red_l[i][n >> 6] = c;
  }
  __syncthreads();
  if (n < 2)
    vout[b0 + n] = red_l[n][0] + red_l[n][1] + red_l[n][2] + red_l[n][3] + Vb2[0];
}

// ---------------------------------------------------------------------------
// Pack W1-bottom (128x256) and W2 (256x256) into bf16 B-fragment order.
// ---------------------------------------------------------------------------
__global__ __launch_bounds__(256) void pack_kernel(
    const float* __restrict__ W1, const float* __restrict__ W2,
    __bf16* __restrict__ W1b_bf, __bf16* __restrict__ W2_bf) {
  const int ts = blockIdx.x * 256 + threadIdx.x;  // 0..12287
  if (ts < 4096) {                                // W1 bottom: t=0..3
    const int t = ts >> 10, rem = ts & 1023, u = rem >> 6, L = rem & 63;
    const int q = L >> 4, l15 = L & 15;
#pragma unroll
    for (int j = 0; j < 8; ++j) {
      const int k = t * 32 + q * 8 + j, nn = u * 16 + l15;
      W1b_bf[ts * 8 + j] = (__bf16)W1[(SD + k) * EMB + nn];
    }
  } else {                                        // W2: t=0..7
    const int ts2 = ts - 4096;
    const int t = ts2 >> 10, rem = ts2 & 1023, u = rem >> 6, L = rem & 63;
    const int q = L >> 4, l15 = L & 15;
#pragma unroll
    for (int j = 0; j < 8; ++j) {
      const int k = t * 32 + q * 8 + j, nn = u * 16 + l15;
      W2_bf[ts2 * 8 + j] = (__bf16)W2[k * EMB + nn];
    }
  }
}

// ---------------------------------------------------------------------------
// Main: 1024 blocks (one per b), 256 threads = 4 waves. Two passes of M=64.
// Column work split in two sequential un-halves: acc[4][2] live (32 regs),
// psum[4][4] carries layer-3 partials across halves.
// ---------------------------------------------------------------------------
__global__ __launch_bounds__(256, 4) void main_kernel(
    const float* __restrict__ agent_qs, const float* __restrict__ b2g,
    const float* __restrict__ W3, const float* __restrict__ b3,
    const float* __restrict__ sW, const float* __restrict__ vv,
    const __bf16* __restrict__ W1b_bf, const __bf16* __restrict__ W2_bf,
    float* __restrict__ out) {
  __shared__ bf16x8 h1_l[32 * 64];      // 32 KB: layer2 A-frags (M=64,K=256)
  __shared__ __attribute__((aligned(16))) __bf16 qs_bf[A_N * NA_N];
  __shared__ float u_l[128];
  __shared__ int   inv_l[128];          // inv_l[s*8+a] = rank of agent a
  __shared__ int   pos_l[128];          // pos_l[s*8+r] = agent with rank r
  __shared__ float adv_part[4][64];
  __shared__ float marg_l[128];         // marginal[s][prefix-row]

  const int b = blockIdx.x;
  const int n = threadIdx.x;
  const int w = n >> 6, L = n & 63, q = L >> 4, l15 = L & 15;

  if (n < 128) {
    qs_bf[n] = (__bf16)agent_qs[b * 128 + n];
    u_l[n] = jax_uniform((unsigned)(b * 128 + n));
  }
  __syncthreads();

  if (n < 128) {
    const int s = n >> 3, a = n & 7;
    const float u = u_l[n];
    int r = 0;
#pragma unroll
    for (int a2 = 0; a2 < A_N; ++a2) {
      const float u2 = u_l[s * 8 + a2];
      r += (u2 < u || (u2 == u && a2 < a)) ? 1 : 0;
    }
    inv_l[n] = r;
    pos_l[s * 8 + r] = a;
  }
  __syncthreads();

  const int i_pref  = l15 & 7;     // prefix length of this lane's row
  const int sl_half = l15 >> 3;    // which s within the mt pair
  const int jq      = q >> 1;      // jcoal low bit
  const int na0     = (q & 1) * 8; // action sub-block

  for (int p = 0; p < 2; ++p) {
    // ---- layer 1: (64x128) @ W1b (128x256), C init sW[col]; 2 un-halves --
#pragma unroll 1
    for (int nh = 0; nh < 2; ++nh) {
      f32x4 acc[4][2];
#pragma unroll
      for (int i = 0; i < 2; ++i) {
        const float sv = sW[b * EMB + (w * 4 + nh * 2 + i) * 16 + l15];
#pragma unroll
        for (int mt = 0; mt < 4; ++mt) acc[mt][i] = splat4(sv);
      }
#pragma unroll 2
      for (int t = 0; t < 4; ++t) {
        const int jcoal = t * 2 + jq;
        const bool on = (jcoal <= i_pref);
        bf16x8 bfr[2];
#pragma unroll
        for (int i = 0; i < 2; ++i)
          bfr[i] = *(const bf16x8*)
              &W1b_bf[((t * 16 + w * 4 + nh * 2 + i) * 64 + L) * 8];
#pragma unroll
        for (int mt = 0; mt < 4; ++mt) {
          const int ag = inv_l[(p * 8 + mt * 2 + sl_half) * 8 + jcoal];
          const bf16x8 qv = *(const bf16x8*)&qs_bf[ag * NA_N + na0];
          const bf16x8 af = on ? qv : zero8();
#pragma unroll
          for (int i = 0; i < 2; ++i)
            acc[mt][i] = __builtin_amdgcn_mfma_f32_16x16x32_bf16(
                af, bfr[i], acc[mt][i], 0, 0, 0);
        }
      }
      // relu -> bf16 scatter into layer2 A-frag layout (frozen formula)
      __bf16* h1e = (__bf16*)h1_l;
#pragma unroll
      for (int i = 0; i < 2; ++i) {
        const int c = (w * 4 + nh * 2 + i) * 16 + l15;
        const int t2 = c >> 5, q2 = (c >> 3) & 3, j2 = l15 & 7;
#pragma unroll
        for (int mt = 0; mt < 4; ++mt) {
#pragma unroll
          for (int r = 0; r < 4; ++r) {
            const float v = fmaxf(acc[mt][i][r], 0.f);
            h1e[(((t2 * 4 + mt) * 64) + q2 * 16 + q * 4 + r) * 8 + j2] =
                (__bf16)v;
          }
        }
      }
    }
    __syncthreads();

    // ---- layer 2 + layer 3 partials: 2 un-halves, psum across halves ----
    float psum[4][4];
#pragma unroll
    for (int mt = 0; mt < 4; ++mt)
#pragma unroll
      for (int r = 0; r < 4; ++r) psum[mt][r] = 0.f;

#pragma unroll 1
    for (int nh = 0; nh < 2; ++nh) {
      f32x4 acc[4][2];
#pragma unroll
      for (int i = 0; i < 2; ++i) {
        const float bv = b2g[(w * 4 + nh * 2 + i) * 16 + l15];
#pragma unroll
        for (int mt = 0; mt < 4; ++mt) acc[mt][i] = splat4(bv);
      }
#pragma unroll 2
      for (int t = 0; t < 8; ++t) {
        bf16x8 bfr[2];
#pragma unroll
        for (int i = 0; i < 2; ++i)
          bfr[i] = *(const bf16x8*)
              &W2_bf[((t * 16 + w * 4 + nh * 2 + i) * 64 + L) * 8];
#pragma unroll
        for (int mt = 0; mt < 4; ++mt) {
          const bf16x8 af = h1_l[(t * 4 + mt) * 64 + L];
#pragma unroll
          for (int i = 0; i < 2; ++i)
            acc[mt][i] = __builtin_amdgcn_mfma_f32_16x16x32_bf16(
                af, bfr[i], acc[mt][i], 0, 0, 0);
        }
      }
#pragma unroll
      for (int i = 0; i < 2; ++i) {
        const float w3v = W3[(w * 4 + nh * 2 + i) * 16 + l15];
#pragma unroll
        for (int mt = 0; mt < 4; ++mt)
#pragma unroll
          for (int r = 0; r < 4; ++r)
            psum[mt][r] = fmaf(fmaxf(acc[mt][i][r], 0.f), w3v, psum[mt][r]);
      }
    }

    // ---- reduce 16 cols per quad, combine waves via LDS ----
#pragma unroll
    for (int mt = 0; mt < 4; ++mt) {
#pragma unroll
      for (int r = 0; r < 4; ++r) {
        float sum = psum[mt][r];
#pragma unroll
        for (int off = 1; off < 16; off <<= 1) sum += __shfl_xor(sum, off);
        if (l15 == 0) adv_part[w][mt * 16 + q * 4 + r] = sum;
      }
    }
    __syncthreads();
    if (n < 64)
      marg_l[p * 64 + n] = adv_part[0][n] + adv_part[1][n] +
                           adv_part[2][n] + adv_part[3][n];
    __syncthreads();
  }

  // ---- gather: agent a reads prefix-row pos_l[s*8+a] (validated) ----
  if (n < A_N) {
    float sh = 0.f;
#pragma unroll
    for (int s = 0; s < S_N; ++s) sh += marg_l[s * 8 + pos_l[s * 8 + n]];
    out[b * A_N + n] = sh * (1.f / 16.f) + b3[0] + vv[b];
  }
}

// ---------------------------------------------------------------------------
extern "C" void kernel_launch(void* const* d_in, const int* in_sizes, int n_in,
                              void* d_out, int out_size, void* d_ws,
                              size_t ws_size, hipStream_t stream) {
  const float* states   = (const float*)d_in[0];
  const float* agent_qs = (const float*)d_in[1];
  const float* W1       = (const float*)d_in[2];
  const float* b1       = (const float*)d_in[3];
  const float* W2       = (const float*)d_in[4];
  const float* b2       = (const float*)d_in[5];
  const float* W3       = (const float*)d_in[6];
  const float* b3       = (const float*)d_in[7];
  const float* Vw1      = (const float*)d_in[8];
  const float* Vb1      = (const float*)d_in[9];
  const float* Vw2      = (const float*)d_in[10];
  const float* Vb2      = (const float*)d_in[11];
  float* out = (float*)d_out;

  char* ws = (char*)d_ws;
  float*  sW     = (float*)(ws);                     // 1 MB
  float*  vv     = (float*)(ws + 1048576);           // 4 KB
  __bf16* W1b_bf = (__bf16*)(ws + 1052672);          // 64 KB
  __bf16* W2_bf  = (__bf16*)(ws + 1118208);          // 128 KB

  prep_kernel<<<512, 256, 0, stream>>>(states, W1, b1, Vw1, Vb1, Vw2, Vb2,
                                       sW, vv);
  pack_kernel<<<48, 256, 0, stream>>>(W1, W2, W1b_bf, W2_bf);
  main_kernel<<<B_TOT, 256, 0, stream>>>(agent_qs, b2, W3, b3, sW, vv,
                                         W1b_bf, W2_bf, out);
}